// Round 1
// baseline (364.346 us; speedup 1.0000x reference)
//
#include <hip/hip_runtime.h>

#define FEAT_D 1024
#define TT 64          // t-tile (one wave's lanes span it)
#define TI 64          // i-chunk per LDS tile
#define PITCH 65       // LDS row pitch: (lane*65 + i) -> bank (lane+i)&31, 2-way free

__global__ __launch_bounds__(256)
void centroid_loss_kernel(const float* __restrict__ centroids,
                          const int*   __restrict__ units,
                          const int*   __restrict__ unit_lengths,
                          const float* __restrict__ Cmat,
                          float*       __restrict__ out,
                          int B, int T)
{
    const int b  = blockIdx.y;
    const int t0 = blockIdx.x * TT;
    const int L  = unit_lengths[b];
    if (t0 >= L) return;   // uniform per block, before any barrier

    __shared__ float tile[TT * PITCH];
    __shared__ float wsum[4];

    const int tid  = threadIdx.x;
    const int lane = tid & 63;
    const int wave = tid >> 6;          // 0..3
    const int t    = t0 + lane;
    const float valid = (t < L) ? 1.0f : 0.0f;

    const float* cent_b  = centroids + (size_t)b * T * FEAT_D;
    const int*   units_b = units + (size_t)b * T;

    float acc = 0.0f;

    for (int chunk = 0; chunk < FEAT_D / TI; ++chunk) {
        const int i0 = chunk * TI;

        // ---- stage 64x64 centroid tile: coalesced float4, lanes along i ----
        {
            const int ii4  = tid & 15;   // which float4 along i
            const int trow = tid >> 4;   // 16 t-rows per pass
            #pragma unroll
            for (int p = 0; p < 4; ++p) {
                const int tt = trow + p * 16;
                const float4 v = *(const float4*)(cent_b + (size_t)(t0 + tt) * FEAT_D + i0 + ii4 * 4);
                float* dst = &tile[tt * PITCH + ii4 * 4];
                dst[0] = v.x; dst[1] = v.y; dst[2] = v.z; dst[3] = v.w;
            }
        }
        __syncthreads();

        // ---- compute: lanes along t; wave handles 16 i-values ----
        const int ibase = i0 + wave * 16;
        #pragma unroll
        for (int k = 0; k < 16; ++k) {
            const int i    = ibase + k;
            const int flat = i * L + t;                 // fits in int: <= 1023*4096+4095
            int r = flat >> 10;
            r = (r < T - 1) ? r : (T - 1);              // keep OOB (masked) lanes in-bounds
            const int c = flat & 1023;
            const int u = units_b[r];                    // wave-near-uniform -> 1-2 lines
            const float cv = Cmat[u * FEAT_D + c];       // ~contiguous 256B per wave
            const float a  = tile[lane * PITCH + (i - i0)];
            acc += valid * fabsf(a - cv);
        }
        __syncthreads();
    }

    // ---- reduce: wave shuffle, then 4 partials via LDS, one atomic ----
    #pragma unroll
    for (int off = 32; off > 0; off >>= 1)
        acc += __shfl_down(acc, off, 64);
    if (lane == 0) wsum[wave] = acc;
    __syncthreads();
    if (tid == 0) {
        const float s = wsum[0] + wsum[1] + wsum[2] + wsum[3];
        atomicAdd(out, s / ((float)L * (float)B));
    }
}

extern "C" void kernel_launch(void* const* d_in, const int* in_sizes, int n_in,
                              void* d_out, int out_size, void* d_ws, size_t ws_size,
                              hipStream_t stream) {
    const float* centroids    = (const float*)d_in[0];
    const int*   units        = (const int*)d_in[1];
    const int*   unit_lengths = (const int*)d_in[2];
    const float* Cmat         = (const float*)d_in[3];
    float* out = (float*)d_out;

    const int B = in_sizes[2];                 // 16
    const int T = in_sizes[1] / B;             // 4096

    hipMemsetAsync(d_out, 0, sizeof(float), stream);

    dim3 grid((T + TT - 1) / TT, B);
    dim3 block(256);
    centroid_loss_kernel<<<grid, block, 0, stream>>>(centroids, units, unit_lengths,
                                                     Cmat, out, B, T);
}